// Round 1
// baseline (2632.455 us; speedup 1.0000x reference)
//
#include <hip/hip_runtime.h>

#define TPB 512
#define BM 64
#define AS 132   // activation row stride in floats (128 + 4 pad)

// ---------------------------------------------------------------------------
// Edge aggregation pass A: sum pos_state[src] into agg_ps[dst] for dst < 2*nvar
// pos_state[src] = +pos_random[src] (src<nvar), -pos_random[src-nvar]
// (nvar<=src<2nvar), 0 otherwise. deg counts ALL edges with dst in range.
// One thread per (edge, quad-of-4-features): 4 floats each.
// ---------------------------------------------------------------------------
__global__ void agg_pos_kernel(const int* __restrict__ ei,
                               const float* __restrict__ pos,
                               float* __restrict__ agg_ps,
                               float* __restrict__ deg_v,
                               int E, int nvar)
{
    int t = blockIdx.x * blockDim.x + threadIdx.x;
    if (t >= E * 4) return;
    int e = t >> 2, q = t & 3;
    int dst = ei[E + e];
    if (dst >= 2 * nvar) return;
    if (q == 0) atomicAdd(deg_v + dst, 1.0f);
    int src = ei[e];
    if (src >= 2 * nvar) return;
    float sgn = 1.0f;
    if (src >= nvar) { src -= nvar; sgn = -1.0f; }
    float4 p = *(const float4*)(pos + (long)src * 16 + q * 4);
    float* d = agg_ps + (long)dst * 16 + q * 4;
    atomicAdd(d + 0, sgn * p.x);
    atomicAdd(d + 1, sgn * p.y);
    atomicAdd(d + 2, sgn * p.z);
    atomicAdd(d + 3, sgn * p.w);
}

// ---------------------------------------------------------------------------
// Edge aggregation pass B: sum node_state[src] (64f) into agg_h[dst-2nvar]
// for dst >= 2nvar; node_state is zero for clause sources (skip).
// One thread per (edge, quad): 16 quads of 4 floats.
// ---------------------------------------------------------------------------
__global__ void agg_cla_kernel(const int* __restrict__ ei,
                               const float* __restrict__ st,
                               float* __restrict__ agg_h,
                               float* __restrict__ deg_c,
                               int E, int nvar2)
{
    int t = blockIdx.x * blockDim.x + threadIdx.x;
    if (t >= E * 16) return;
    int e = t >> 4, q = t & 15;
    int dst = ei[E + e];
    if (dst < nvar2) return;
    int cd = dst - nvar2;
    if (q == 0) atomicAdd(deg_c + cd, 1.0f);
    int src = ei[e];
    if (src >= nvar2) return;
    float4 v = *(const float4*)(st + (long)src * 64 + q * 4);
    float* d = agg_h + (long)cd * 64 + q * 4;
    atomicAdd(d + 0, v.x);
    atomicAdd(d + 1, v.y);
    atomicAdd(d + 2, v.z);
    atomicAdd(d + 3, v.w);
}

// ---------------------------------------------------------------------------
// Generic tiled GEMM layer: actOut[r][c] = f(sum_k actIn[r][k]*wb[k][c] +
// scale(r)*bias[c]).  BM=64 rows, C columns (64 or 128), 512 threads.
// Thread tile: 4 rows x CPT cols (CPT = C/32).
// actIn/actOut are LDS [64][AS] row-major; wb is LDS [K][C] packed.
// ---------------------------------------------------------------------------
template<int CPT>
__device__ __forceinline__ void gemm_layer(
    const float* __restrict__ actIn, const float* __restrict__ wb,
    const float* __restrict__ bias_g, const float* __restrict__ ldeg,
    int K, int C, bool relu, float* __restrict__ actOut,
    float* __restrict__ state_g, long base, int n)
{
    const int tid = threadIdx.x;
    const int tx = tid & 31;
    const int ty = tid >> 5;           // 0..15
    const int r0 = ty * 4;
    const int c0 = tx * CPT;

    float acc[4][CPT];
#pragma unroll
    for (int i = 0; i < 4; i++)
#pragma unroll
        for (int j = 0; j < CPT; j++) acc[i][j] = 0.0f;

    for (int k = 0; k < K; k += 4) {
        float4 a0 = *(const float4*)(actIn + (r0 + 0) * AS + k);
        float4 a1 = *(const float4*)(actIn + (r0 + 1) * AS + k);
        float4 a2 = *(const float4*)(actIn + (r0 + 2) * AS + k);
        float4 a3 = *(const float4*)(actIn + (r0 + 3) * AS + k);
#pragma unroll
        for (int kk = 0; kk < 4; kk++) {
            float b[CPT];
            if (CPT == 4) {
                float4 bv = *(const float4*)(wb + (k + kk) * C + c0);
                b[0] = bv.x; b[1] = bv.y; b[2] = bv.z; b[3] = bv.w;
            } else {
                float2 bv = *(const float2*)(wb + (k + kk) * C + c0);
                b[0] = bv.x; b[1] = bv.y;
            }
            float av[4];
            av[0] = ((const float*)&a0)[kk];
            av[1] = ((const float*)&a1)[kk];
            av[2] = ((const float*)&a2)[kk];
            av[3] = ((const float*)&a3)[kk];
#pragma unroll
            for (int i = 0; i < 4; i++)
#pragma unroll
                for (int j = 0; j < CPT; j++)
                    acc[i][j] = fmaf(av[i], b[j], acc[i][j]);
        }
    }

#pragma unroll
    for (int i = 0; i < 4; i++) {
        int r = r0 + i;
        float scale = ldeg ? ldeg[r] : 1.0f;
#pragma unroll
        for (int j = 0; j < CPT; j++) {
            int c = c0 + j;
            float v = acc[i][j] + scale * bias_g[c];
            if (relu) v = fmaxf(v, 0.0f);
            actOut[r * AS + c] = v;
            if (state_g != nullptr && base + r < n)
                state_g[(base + r) * 64 + c] = v;
        }
    }
}

__device__ __forceinline__ void stage_w(const float* __restrict__ W,
                                        float* __restrict__ wbuf, int nfloats)
{
    const float4* src = (const float4*)W;
    float4* dst = (float4*)wbuf;
    for (int i = threadIdx.x; i < (nfloats >> 2); i += TPB) dst[i] = src[i];
}

// ---------------------------------------------------------------------------
// Fused per-64-node-tile MLP chain:
//   msg = agg@W0 + deg*b0            (K0 -> 64, no relu)
//   h   = concat(msg, x)             (67, pad to 68 with zeros)
//   update MLP: 68->128 relu, 128->128 relu, 128->64 (state, written to global
//     for the vn partition so pass B can aggregate it)
//   predictor:  64->128 relu, 128->128 relu, 128->2 -> out
// Weights staged per-layer into a 64KB LDS buffer; activations ping-pong.
// ---------------------------------------------------------------------------
template<int K0>
__global__ __launch_bounds__(TPB, 2)
void fused_kernel(const float* __restrict__ agg, const float* __restrict__ deg,
                  const float* __restrict__ xg,
                  const float* __restrict__ W0, const float* __restrict__ b0,
                  const float* __restrict__ uW1, const float* __restrict__ ub1,
                  const float* __restrict__ uW2, const float* __restrict__ ub2,
                  const float* __restrict__ uW3, const float* __restrict__ ub3,
                  const float* __restrict__ pW1, const float* __restrict__ pb1,
                  const float* __restrict__ pW2, const float* __restrict__ pb2,
                  const float* __restrict__ pW3, const float* __restrict__ pb3,
                  float* __restrict__ state_g, float* __restrict__ outg, int n)
{
    __shared__ float actA[BM * AS];
    __shared__ float actB[BM * AS];
    __shared__ float wbuf[128 * 128];
    __shared__ float ldeg[BM];

    const int tid = threadIdx.x;
    const long base = (long)blockIdx.x * BM;

    // ---- Phase A: stage agg -> actA[:, 0:K0], deg -> ldeg, W0 -> wbuf
    {
        const int CH = K0 / 2;  // float2 chunks per node
        for (int idx = tid; idx < BM * CH; idx += TPB) {
            int node = idx / CH, j2 = idx % CH;
            float2 v = make_float2(0.0f, 0.0f);
            if (base + node < n)
                v = *(const float2*)(agg + (base + node) * (long)K0 + j2 * 2);
            *(float2*)(actA + node * AS + j2 * 2) = v;
        }
        if (tid < BM) ldeg[tid] = (base + tid < n) ? deg[base + tid] : 0.0f;
        stage_w(W0, wbuf, K0 * 64);
    }
    __syncthreads();

    // ---- layer0: msg = agg@W0 + deg*b0 -> actB[:, 0:64]; stage x -> cols 64..66
    gemm_layer<2>(actA, wbuf, b0, ldeg, K0, 64, false, actB, nullptr, base, n);
    for (int idx = tid; idx < BM * 3; idx += TPB) {
        int node = idx / 3, j = idx % 3;
        float v = (base + node < n) ? xg[(base + node) * 3 + j] : 0.0f;
        actB[node * AS + 64 + j] = v;
    }
    if (tid < BM) actB[tid * AS + 67] = 0.0f;  // zero pad col 67
    __syncthreads();

    // ---- update layer1: 68 -> 128 relu (uW1 is 67x128, pad row 67 with zeros)
    stage_w(uW1, wbuf, 67 * 128);
    for (int i = tid; i < 32; i += TPB)
        ((float4*)wbuf)[2144 + i] = make_float4(0.f, 0.f, 0.f, 0.f);
    __syncthreads();
    gemm_layer<4>(actB, wbuf, ub1, nullptr, 68, 128, true, actA, nullptr, base, n);
    __syncthreads();

    // ---- update layer2: 128 -> 128 relu
    stage_w(uW2, wbuf, 128 * 128);
    __syncthreads();
    gemm_layer<4>(actA, wbuf, ub2, nullptr, 128, 128, true, actB, nullptr, base, n);
    __syncthreads();

    // ---- update layer3: 128 -> 64 (no relu) = node state; write global if vn
    stage_w(uW3, wbuf, 128 * 64);
    __syncthreads();
    gemm_layer<2>(actB, wbuf, ub3, nullptr, 128, 64, false, actA, state_g, base, n);
    __syncthreads();

    // ---- predictor layer1: 64 -> 128 relu
    stage_w(pW1, wbuf, 64 * 128);
    __syncthreads();
    gemm_layer<4>(actA, wbuf, pb1, nullptr, 64, 128, true, actB, nullptr, base, n);
    __syncthreads();

    // ---- predictor layer2: 128 -> 128 relu
    stage_w(pW2, wbuf, 128 * 128);
    __syncthreads();
    gemm_layer<4>(actB, wbuf, pb2, nullptr, 128, 128, true, actA, nullptr, base, n);
    __syncthreads();

    // ---- predictor layer3: 128 -> 2, write output
    stage_w(pW3, wbuf, 128 * 2);
    __syncthreads();
    if (tid < 128) {
        int r = tid >> 1, c = tid & 1;
        float acc = pb3[c];
        for (int k = 0; k < 128; k += 4) {
            float4 a = *(const float4*)(actA + r * AS + k);
            acc = fmaf(a.x, wbuf[(k + 0) * 2 + c], acc);
            acc = fmaf(a.y, wbuf[(k + 1) * 2 + c], acc);
            acc = fmaf(a.z, wbuf[(k + 2) * 2 + c], acc);
            acc = fmaf(a.w, wbuf[(k + 3) * 2 + c], acc);
        }
        if (base + r < n) outg[(base + r) * 2 + c] = acc;
    }
}

// ---------------------------------------------------------------------------
extern "C" void kernel_launch(void* const* d_in, const int* in_sizes, int n_in,
                              void* d_out, int out_size, void* d_ws, size_t ws_size,
                              hipStream_t stream)
{
    const float* x    = (const float*)d_in[0];
    const int*   ei   = (const int*)d_in[1];
    // d_in[2] = gate_type: ordering is [VAR*nvar, NEGVAR*nvar, CLAUSE*ncla] — ranges suffice
    const float* posr = (const float*)d_in[3];
    const float* Wr   = (const float*)d_in[4];
    const float* br   = (const float*)d_in[5];
    const float* Wc   = (const float*)d_in[6];
    const float* bc   = (const float*)d_in[7];
    const float* uW1  = (const float*)d_in[8];
    const float* ub1  = (const float*)d_in[9];
    const float* uW2  = (const float*)d_in[10];
    const float* ub2  = (const float*)d_in[11];
    const float* uW3  = (const float*)d_in[12];
    const float* ub3  = (const float*)d_in[13];
    const float* pW1  = (const float*)d_in[14];
    const float* pb1  = (const float*)d_in[15];
    const float* pW2  = (const float*)d_in[16];
    const float* pb2  = (const float*)d_in[17];
    const float* pW3  = (const float*)d_in[18];
    const float* pb3  = (const float*)d_in[19];

    const int N     = in_sizes[0] / 3;
    const int E     = in_sizes[1] / 2;
    const int nvar  = in_sizes[3] / 16;
    const int nvar2 = 2 * nvar;
    const int ncla  = N - nvar2;

    // workspace carve-out (floats)
    float* ws     = (float*)d_ws;
    float* agg_ps = ws;                                  // [2nvar][16]
    float* deg_v  = agg_ps + (size_t)nvar2 * 16;         // [2nvar]
    float* agg_h  = deg_v + nvar2;                       // [ncla][64]
    float* deg_c  = agg_h + (size_t)ncla * 64;           // [ncla]
    float* state  = deg_c + ncla;                        // [2nvar][64]
    size_t zero_floats = (size_t)nvar2 * 17 + (size_t)ncla * 65;

    hipMemsetAsync(agg_ps, 0, zero_floats * sizeof(float), stream);

    {   // pass A: pos_state aggregation into var/negvar destinations
        int total = E * 4;
        int blocks = (total + 255) / 256;
        agg_pos_kernel<<<blocks, 256, 0, stream>>>(ei, posr, agg_ps, deg_v, E, nvar);
    }

    {   // var + negvar partitions: layer0(Wr) + update MLP + predictor, write state
        int blocks = (nvar2 + BM - 1) / BM;
        fused_kernel<16><<<blocks, TPB, 0, stream>>>(
            agg_ps, deg_v, x, Wr, br,
            uW1, ub1, uW2, ub2, uW3, ub3,
            pW1, pb1, pW2, pb2, pW3, pb3,
            state, (float*)d_out, nvar2);
    }

    {   // pass B: node_state aggregation into clause destinations
        int total = E * 16;
        int blocks = (total + 255) / 256;
        agg_cla_kernel<<<blocks, 256, 0, stream>>>(ei, state, agg_h, deg_c, E, nvar2);
    }

    {   // clause partition: layer0(Wc) + update MLP + predictor
        int blocks = (ncla + BM - 1) / BM;
        fused_kernel<64><<<blocks, TPB, 0, stream>>>(
            agg_h, deg_c, x + (size_t)nvar2 * 3, Wc, bc,
            uW1, ub1, uW2, ub2, uW3, ub3,
            pW1, pb1, pW2, pb2, pW3, pb3,
            nullptr, (float*)d_out + (size_t)nvar2 * 2, ncla);
    }
}

// Round 2
// 2090.784 us; speedup vs baseline: 1.2591x; 1.2591x over previous
//
#include <hip/hip_runtime.h>

#define TPB 512
#define BM 64
#define AS 128   // activation row stride in floats

// ---------------------------------------------------------------------------
// Edge aggregation pass A: sum pos_state[src] into agg_ps[dst] for dst < 2*nvar
// pos_state[src] = +pos_random[src] (src<nvar), -pos_random[src-nvar]
// (nvar<=src<2nvar), 0 otherwise. deg counts ALL edges with dst in range.
// ---------------------------------------------------------------------------
__global__ void agg_pos_kernel(const int* __restrict__ ei,
                               const float* __restrict__ pos,
                               float* __restrict__ agg_ps,
                               float* __restrict__ deg_v,
                               int E, int nvar)
{
    int t = blockIdx.x * blockDim.x + threadIdx.x;
    if (t >= E * 4) return;
    int e = t >> 2, q = t & 3;
    int dst = ei[E + e];
    if (dst >= 2 * nvar) return;
    if (q == 0) atomicAdd(deg_v + dst, 1.0f);
    int src = ei[e];
    if (src >= 2 * nvar) return;
    float sgn = 1.0f;
    if (src >= nvar) { src -= nvar; sgn = -1.0f; }
    float4 p = *(const float4*)(pos + (long)src * 16 + q * 4);
    float* d = agg_ps + (long)dst * 16 + q * 4;
    atomicAdd(d + 0, sgn * p.x);
    atomicAdd(d + 1, sgn * p.y);
    atomicAdd(d + 2, sgn * p.z);
    atomicAdd(d + 3, sgn * p.w);
}

// ---------------------------------------------------------------------------
// Edge aggregation pass B: sum node_state[src] (64f) into agg_h[dst-2nvar]
// for dst >= 2nvar; node_state is zero for clause sources (skip).
// ---------------------------------------------------------------------------
__global__ void agg_cla_kernel(const int* __restrict__ ei,
                               const float* __restrict__ st,
                               float* __restrict__ agg_h,
                               float* __restrict__ deg_c,
                               int E, int nvar2)
{
    int t = blockIdx.x * blockDim.x + threadIdx.x;
    if (t >= E * 16) return;
    int e = t >> 4, q = t & 15;
    int dst = ei[E + e];
    if (dst < nvar2) return;
    int cd = dst - nvar2;
    if (q == 0) atomicAdd(deg_c + cd, 1.0f);
    int src = ei[e];
    if (src >= nvar2) return;
    float4 v = *(const float4*)(st + (long)src * 64 + q * 4);
    float* d = agg_h + (long)cd * 64 + q * 4;
    atomicAdd(d + 0, v.x);
    atomicAdd(d + 1, v.y);
    atomicAdd(d + 2, v.z);
    atomicAdd(d + 3, v.w);
}

// ---------------------------------------------------------------------------
// Tiled GEMM layer with CHUNKED weight staging (8 KB LDS chunk):
//   actOut[r][c] = f(sum_k actIn[r][k]*W[k][c] + scale(r)*bias[c])
// C = CPT*32 (64 or 128). Weights staged 2048 floats at a time inside the
// k-loop; with 2 blocks/CU, staging of one block overlaps FMAs of the other.
// Rows of W beyond K_real are staged as zeros (covers the 67->68 pad).
// ---------------------------------------------------------------------------
template<int CPT>
__device__ __forceinline__ void gemm_layer(
    const float* __restrict__ actIn, const float* __restrict__ Wg,
    const float* __restrict__ bias_g, const float* __restrict__ ldeg,
    float* __restrict__ wchunk,
    int K_real, int K_pad, bool relu, float* __restrict__ actOut,
    float* __restrict__ state_g, long base, int n)
{
    constexpr int C = CPT * 32;
    constexpr int RPC = 2048 / C;    // rows per 8KB chunk: 16 (C=128) / 32 (C=64)
    const int tid = threadIdx.x;
    const int tx = tid & 31;
    const int ty = tid >> 5;         // 0..15
    const int r0 = ty * 4;
    const int c0 = tx * CPT;

    float acc[4][CPT];
#pragma unroll
    for (int i = 0; i < 4; i++)
#pragma unroll
        for (int j = 0; j < CPT; j++) acc[i][j] = 0.0f;

    for (int kb = 0; kb < K_pad; kb += RPC) {
        int rows = K_pad - kb; if (rows > RPC) rows = RPC;
        // ---- stage W rows kb..kb+rows-1 into wchunk (zero beyond K_real)
        int nq = (rows * C) >> 2;
        for (int i = tid; i < nq; i += TPB) {
            int fo = i << 2;
            int r = fo / C;
            int gk = kb + r;
            float4 v = make_float4(0.f, 0.f, 0.f, 0.f);
            if (gk < K_real) v = *(const float4*)(Wg + (long)gk * C + (fo - r * C));
            ((float4*)wchunk)[i] = v;
        }
        __syncthreads();
        // ---- accumulate over this chunk
        for (int k = 0; k < rows; k += 4) {
            float4 a0 = *(const float4*)(actIn + (r0 + 0) * AS + kb + k);
            float4 a1 = *(const float4*)(actIn + (r0 + 1) * AS + kb + k);
            float4 a2 = *(const float4*)(actIn + (r0 + 2) * AS + kb + k);
            float4 a3 = *(const float4*)(actIn + (r0 + 3) * AS + kb + k);
#pragma unroll
            for (int kk = 0; kk < 4; kk++) {
                float b[CPT];
                if (CPT == 4) {
                    float4 bv = *(const float4*)(wchunk + (k + kk) * C + c0);
                    b[0] = bv.x; b[1] = bv.y; b[2] = bv.z; b[3] = bv.w;
                } else {
                    float2 bv = *(const float2*)(wchunk + (k + kk) * C + c0);
                    b[0] = bv.x; b[1] = bv.y;
                }
                float av[4];
                av[0] = ((const float*)&a0)[kk];
                av[1] = ((const float*)&a1)[kk];
                av[2] = ((const float*)&a2)[kk];
                av[3] = ((const float*)&a3)[kk];
#pragma unroll
                for (int i = 0; i < 4; i++)
#pragma unroll
                    for (int j = 0; j < CPT; j++)
                        acc[i][j] = fmaf(av[i], b[j], acc[i][j]);
            }
        }
        __syncthreads();   // wchunk safe to overwrite (also orders act ping-pong)
    }

#pragma unroll
    for (int i = 0; i < 4; i++) {
        int r = r0 + i;
        float scale = ldeg ? ldeg[r] : 1.0f;
#pragma unroll
        for (int j = 0; j < CPT; j++) {
            int c = c0 + j;
            float v = acc[i][j] + scale * bias_g[c];
            if (relu) v = fmaxf(v, 0.0f);
            actOut[r * AS + c] = v;
            if (state_g != nullptr && base + r < n)
                state_g[(base + r) * 64 + c] = v;
        }
    }
}

// ---------------------------------------------------------------------------
// Fused per-64-node-tile MLP chain:
//   msg = agg@W0 + deg*b0  (K0 -> 64)
//   h = concat(msg, x) (67 -> pad 68)
//   update MLP: 68->128 relu, 128->128 relu, 128->64 (state -> global for vn)
//   predictor:  64->128 relu, 128->128 relu, 128->2 -> out
// LDS ~74 KB -> 2 blocks/CU (16 waves).
// ---------------------------------------------------------------------------
template<int K0>
__global__ __launch_bounds__(TPB, 4)
void fused_kernel(const float* __restrict__ agg, const float* __restrict__ deg,
                  const float* __restrict__ xg,
                  const float* __restrict__ W0, const float* __restrict__ b0,
                  const float* __restrict__ uW1, const float* __restrict__ ub1,
                  const float* __restrict__ uW2, const float* __restrict__ ub2,
                  const float* __restrict__ uW3, const float* __restrict__ ub3,
                  const float* __restrict__ pW1, const float* __restrict__ pb1,
                  const float* __restrict__ pW2, const float* __restrict__ pb2,
                  const float* __restrict__ pW3, const float* __restrict__ pb3,
                  float* __restrict__ state_g, float* __restrict__ outg, int n)
{
    __shared__ float actA[BM * AS];
    __shared__ float actB[BM * AS];
    __shared__ float wchunk[2048];
    __shared__ float ldeg[BM];

    const int tid = threadIdx.x;
    const long base = (long)blockIdx.x * BM;

    // ---- stage agg -> actA[:, 0:K0], deg -> ldeg
    {
        const int CH = K0 / 2;
        for (int idx = tid; idx < BM * CH; idx += TPB) {
            int node = idx / CH, j2 = idx % CH;
            float2 v = make_float2(0.0f, 0.0f);
            if (base + node < n)
                v = *(const float2*)(agg + (base + node) * (long)K0 + j2 * 2);
            *(float2*)(actA + node * AS + j2 * 2) = v;
        }
        if (tid < BM) ldeg[tid] = (base + tid < n) ? deg[base + tid] : 0.0f;
    }
    __syncthreads();

    // ---- layer0: msg = agg@W0 + deg*b0 -> actB[:, 0:64]
    gemm_layer<2>(actA, W0, b0, ldeg, wchunk, K0, K0, false, actB, nullptr, base, n);
    // stage x -> actB cols 64..66, zero col 67
    for (int idx = tid; idx < BM * 3; idx += TPB) {
        int node = idx / 3, j = idx % 3;
        float v = (base + node < n) ? xg[(base + node) * 3 + j] : 0.0f;
        actB[node * AS + 64 + j] = v;
    }
    if (tid < BM) actB[tid * AS + 67] = 0.0f;

    // ---- update MLP (x-stage writes are ordered by the first chunk-sync below)
    gemm_layer<4>(actB, uW1, ub1, nullptr, wchunk, 67, 68, true, actA, nullptr, base, n);
    gemm_layer<4>(actA, uW2, ub2, nullptr, wchunk, 128, 128, true, actB, nullptr, base, n);
    gemm_layer<2>(actB, uW3, ub3, nullptr, wchunk, 128, 128, false, actA, state_g, base, n);

    // ---- predictor MLP
    gemm_layer<4>(actA, pW1, pb1, nullptr, wchunk, 64, 64, true, actB, nullptr, base, n);
    gemm_layer<4>(actB, pW2, pb2, nullptr, wchunk, 128, 128, true, actA, nullptr, base, n);

    // ---- predictor layer3: 128 -> 2
    for (int i = tid; i < 64; i += TPB)
        ((float4*)wchunk)[i] = ((const float4*)pW3)[i];
    __syncthreads();
    if (tid < 128) {
        int r = tid >> 1, c = tid & 1;
        float acc = pb3[c];
        for (int k = 0; k < 128; k += 4) {
            float4 a = *(const float4*)(actA + r * AS + k);
            acc = fmaf(a.x, wchunk[(k + 0) * 2 + c], acc);
            acc = fmaf(a.y, wchunk[(k + 1) * 2 + c], acc);
            acc = fmaf(a.z, wchunk[(k + 2) * 2 + c], acc);
            acc = fmaf(a.w, wchunk[(k + 3) * 2 + c], acc);
        }
        if (base + r < n) outg[(base + r) * 2 + c] = acc;
    }
}

// ---------------------------------------------------------------------------
extern "C" void kernel_launch(void* const* d_in, const int* in_sizes, int n_in,
                              void* d_out, int out_size, void* d_ws, size_t ws_size,
                              hipStream_t stream)
{
    const float* x    = (const float*)d_in[0];
    const int*   ei   = (const int*)d_in[1];
    // d_in[2] = gate_type: fixed ordering [VAR*nvar, NEGVAR*nvar, CLAUSE*ncla]
    const float* posr = (const float*)d_in[3];
    const float* Wr   = (const float*)d_in[4];
    const float* br   = (const float*)d_in[5];
    const float* Wc   = (const float*)d_in[6];
    const float* bc   = (const float*)d_in[7];
    const float* uW1  = (const float*)d_in[8];
    const float* ub1  = (const float*)d_in[9];
    const float* uW2  = (const float*)d_in[10];
    const float* ub2  = (const float*)d_in[11];
    const float* uW3  = (const float*)d_in[12];
    const float* ub3  = (const float*)d_in[13];
    const float* pW1  = (const float*)d_in[14];
    const float* pb1  = (const float*)d_in[15];
    const float* pW2  = (const float*)d_in[16];
    const float* pb2  = (const float*)d_in[17];
    const float* pW3  = (const float*)d_in[18];
    const float* pb3  = (const float*)d_in[19];

    const int N     = in_sizes[0] / 3;
    const int E     = in_sizes[1] / 2;
    const int nvar  = in_sizes[3] / 16;
    const int nvar2 = 2 * nvar;
    const int ncla  = N - nvar2;

    // workspace carve-out (floats)
    float* ws     = (float*)d_ws;
    float* agg_ps = ws;                                  // [2nvar][16]
    float* deg_v  = agg_ps + (size_t)nvar2 * 16;         // [2nvar]
    float* agg_h  = deg_v + nvar2;                       // [ncla][64]
    float* deg_c  = agg_h + (size_t)ncla * 64;           // [ncla]
    float* state  = deg_c + ncla;                        // [2nvar][64]
    size_t zero_floats = (size_t)nvar2 * 17 + (size_t)ncla * 65;

    hipMemsetAsync(agg_ps, 0, zero_floats * sizeof(float), stream);

    {   // pass A: pos_state aggregation into var/negvar destinations
        int total = E * 4;
        int blocks = (total + 255) / 256;
        agg_pos_kernel<<<blocks, 256, 0, stream>>>(ei, posr, agg_ps, deg_v, E, nvar);
    }

    {   // var + negvar partitions
        int blocks = (nvar2 + BM - 1) / BM;
        fused_kernel<16><<<blocks, TPB, 0, stream>>>(
            agg_ps, deg_v, x, Wr, br,
            uW1, ub1, uW2, ub2, uW3, ub3,
            pW1, pb1, pW2, pb2, pW3, pb3,
            state, (float*)d_out, nvar2);
    }

    {   // pass B: node_state aggregation into clause destinations
        int total = E * 16;
        int blocks = (total + 255) / 256;
        agg_cla_kernel<<<blocks, 256, 0, stream>>>(ei, state, agg_h, deg_c, E, nvar2);
    }

    {   // clause partition
        int blocks = (ncla + BM - 1) / BM;
        fused_kernel<64><<<blocks, TPB, 0, stream>>>(
            agg_h, deg_c, x + (size_t)nvar2 * 3, Wc, bc,
            uW1, ub1, uW2, ub2, uW3, ub3,
            pW1, pb1, pW2, pb2, pW3, pb3,
            nullptr, (float*)d_out + (size_t)nvar2 * 2, ncla);
    }
}

// Round 3
// 1620.951 us; speedup vs baseline: 1.6240x; 1.2899x over previous
//
#include <hip/hip_runtime.h>

#define TPB 512
#define BM 64
#define AS 128   // activation row stride in floats

// ===========================================================================
// CSR build: count -> block scan -> fixup -> scatter. Rebuilt every call
// (no caching allowed). dst-keyed over ALL edges; row length == degree.
// ===========================================================================
__global__ void count_kernel(const int* __restrict__ ei, int* __restrict__ cnt, int E)
{
    int e = blockIdx.x * blockDim.x + threadIdx.x;
    if (e >= E) return;
    atomicAdd(cnt + ei[E + e], 1);
}

// per-block exclusive scan over 2048 elements; emits block totals
__global__ void scan_blocks(const int* __restrict__ cnt, int* __restrict__ rs,
                            int* __restrict__ part, int N)
{
    __shared__ int sums[256];
    int t = threadIdx.x;
    int base = blockIdx.x * 2048 + t * 8;
    int v[8], s = 0;
#pragma unroll
    for (int i = 0; i < 8; i++) { int idx = base + i; v[i] = (idx < N) ? cnt[idx] : 0; s += v[i]; }
    sums[t] = s;
    __syncthreads();
    for (int off = 1; off < 256; off <<= 1) {
        int x = (t >= off) ? sums[t - off] : 0;
        __syncthreads();
        if (t >= off) sums[t] += x;
        __syncthreads();
    }
    int run = (t == 0) ? 0 : sums[t - 1];
#pragma unroll
    for (int i = 0; i < 8; i++) { int idx = base + i; if (idx < N) rs[idx] = run; run += v[i]; }
    if (t == 255) part[blockIdx.x] = sums[255];
}

// single-block exclusive scan of block totals (nb <= 2048), in place
__global__ void scan_part(int* __restrict__ part, int nb)
{
    __shared__ int sums[256];
    int t = threadIdx.x;
    int base = t * 8;
    int v[8], s = 0;
#pragma unroll
    for (int i = 0; i < 8; i++) { int idx = base + i; v[i] = (idx < nb) ? part[idx] : 0; s += v[i]; }
    sums[t] = s;
    __syncthreads();
    for (int off = 1; off < 256; off <<= 1) {
        int x = (t >= off) ? sums[t - off] : 0;
        __syncthreads();
        if (t >= off) sums[t] += x;
        __syncthreads();
    }
    int run = (t == 0) ? 0 : sums[t - 1];
#pragma unroll
    for (int i = 0; i < 8; i++) { int idx = base + i; if (idx < nb) part[idx] = run; run += v[i]; }
}

__global__ void scan_fixup(int* __restrict__ rs, int* __restrict__ cursor,
                           const int* __restrict__ part, int N, int E)
{
    int i = blockIdx.x * blockDim.x + threadIdx.x;
    if (i < N) { int v = rs[i] + part[i >> 11]; rs[i] = v; cursor[i] = v; }
    if (i == 0) rs[N] = E;
}

__global__ void scatter_kernel(const int* __restrict__ ei, int* __restrict__ cursor,
                               int* __restrict__ col, int E)
{
    int e = blockIdx.x * blockDim.x + threadIdx.x;
    if (e >= E) return;
    int d = ei[E + e];
    int p = atomicAdd(cursor + d, 1);
    col[p] = ei[e];
}

// ===========================================================================
// Tiled GEMM layer with chunked (8 KB) LDS weight staging.
// actOut[r][c] = f(sum_k actIn[r][k]*W[k][c] + scale(r)*bias[c])
// ===========================================================================
template<int CPT>
__device__ __forceinline__ void gemm_layer(
    const float* __restrict__ actIn, const float* __restrict__ Wg,
    const float* __restrict__ bias_g, const float* __restrict__ ldeg,
    float* __restrict__ wchunk,
    int K_real, int K_pad, bool relu, float* __restrict__ actOut,
    float* __restrict__ state_g, long base, int n)
{
    constexpr int C = CPT * 32;
    constexpr int RPC = 2048 / C;    // rows per 8KB chunk
    const int tid = threadIdx.x;
    const int tx = tid & 31;
    const int ty = tid >> 5;
    const int r0 = ty * 4;
    const int c0 = tx * CPT;

    float acc[4][CPT];
#pragma unroll
    for (int i = 0; i < 4; i++)
#pragma unroll
        for (int j = 0; j < CPT; j++) acc[i][j] = 0.0f;

    for (int kb = 0; kb < K_pad; kb += RPC) {
        int rows = K_pad - kb; if (rows > RPC) rows = RPC;
        int nq = (rows * C) >> 2;
        for (int i = tid; i < nq; i += TPB) {
            int fo = i << 2;
            int r = fo / C;
            int gk = kb + r;
            float4 v = make_float4(0.f, 0.f, 0.f, 0.f);
            if (gk < K_real) v = *(const float4*)(Wg + (long)gk * C + (fo - r * C));
            ((float4*)wchunk)[i] = v;
        }
        __syncthreads();
        for (int k = 0; k < rows; k += 4) {
            float4 a0 = *(const float4*)(actIn + (r0 + 0) * AS + kb + k);
            float4 a1 = *(const float4*)(actIn + (r0 + 1) * AS + kb + k);
            float4 a2 = *(const float4*)(actIn + (r0 + 2) * AS + kb + k);
            float4 a3 = *(const float4*)(actIn + (r0 + 3) * AS + kb + k);
#pragma unroll
            for (int kk = 0; kk < 4; kk++) {
                float b[CPT];
                if (CPT == 4) {
                    float4 bv = *(const float4*)(wchunk + (k + kk) * C + c0);
                    b[0] = bv.x; b[1] = bv.y; b[2] = bv.z; b[3] = bv.w;
                } else {
                    float2 bv = *(const float2*)(wchunk + (k + kk) * C + c0);
                    b[0] = bv.x; b[1] = bv.y;
                }
                float av[4];
                av[0] = ((const float*)&a0)[kk];
                av[1] = ((const float*)&a1)[kk];
                av[2] = ((const float*)&a2)[kk];
                av[3] = ((const float*)&a3)[kk];
#pragma unroll
                for (int i = 0; i < 4; i++)
#pragma unroll
                    for (int j = 0; j < CPT; j++)
                        acc[i][j] = fmaf(av[i], b[j], acc[i][j]);
            }
        }
        __syncthreads();
    }

#pragma unroll
    for (int i = 0; i < 4; i++) {
        int r = r0 + i;
        float scale = ldeg ? ldeg[r] : 1.0f;
#pragma unroll
        for (int j = 0; j < CPT; j++) {
            int c = c0 + j;
            float v = acc[i][j] + scale * bias_g[c];
            if (relu) v = fmaxf(v, 0.0f);
            actOut[r * AS + c] = v;
            if (state_g != nullptr && base + r < n)
                state_g[(base + r) * 64 + c] = v;
        }
    }
}

// ===========================================================================
// Fused per-64-node-tile: CSR gather -> layer0 -> update MLP -> predictor.
// K0=16 (var/negvar, srcdat=pos_random with +/- sign) or
// K0=64 (clause, srcdat=state; rs pre-offset by 2*nvar).
// ===========================================================================
template<int K0>
__global__ __launch_bounds__(TPB, 4)
void fused_kernel(const int* __restrict__ rs, const int* __restrict__ col,
                  const float* __restrict__ srcdat, int nvar,
                  const float* __restrict__ xg,
                  const float* __restrict__ W0, const float* __restrict__ b0,
                  const float* __restrict__ uW1, const float* __restrict__ ub1,
                  const float* __restrict__ uW2, const float* __restrict__ ub2,
                  const float* __restrict__ uW3, const float* __restrict__ ub3,
                  const float* __restrict__ pW1, const float* __restrict__ pb1,
                  const float* __restrict__ pW2, const float* __restrict__ pb2,
                  const float* __restrict__ pW3, const float* __restrict__ pb3,
                  float* __restrict__ state_g, float* __restrict__ outg, int n)
{
    __shared__ float actA[BM * AS];
    __shared__ float actB[BM * AS];
    __shared__ float wchunk[2048];
    __shared__ float ldeg[BM];

    const int tid = threadIdx.x;
    const long base = (long)blockIdx.x * BM;
    const int nvar2 = 2 * nvar;
    const int wave = tid >> 6;
    const int lane = tid & 63;

    // ---- CSR gather into actA[:, 0:K0]; deg -> ldeg
    if constexpr (K0 == 64) {
        // wave handles 8 nodes sequentially; 64 lanes = 64 features
        for (int i = 0; i < 8; i++) {
            int node = wave * 8 + i;
            long g = base + node;
            int d0 = 0, d1 = 0;
            if (g < n) { d0 = rs[g]; d1 = rs[g + 1]; }
            float acc = 0.0f;
            int e = d0;
            for (; e + 4 <= d1; e += 4) {
                int s0 = col[e], s1 = col[e + 1], s2 = col[e + 2], s3 = col[e + 3];
                float a0 = (s0 < nvar2) ? srcdat[(long)s0 * 64 + lane] : 0.0f;
                float a1 = (s1 < nvar2) ? srcdat[(long)s1 * 64 + lane] : 0.0f;
                float a2 = (s2 < nvar2) ? srcdat[(long)s2 * 64 + lane] : 0.0f;
                float a3 = (s3 < nvar2) ? srcdat[(long)s3 * 64 + lane] : 0.0f;
                acc += a0 + a1 + a2 + a3;
            }
            for (; e < d1; e++) {
                int s = col[e];
                if (s < nvar2) acc += srcdat[(long)s * 64 + lane];
            }
            actA[node * AS + lane] = acc;
            if (lane == 0) ldeg[node] = (float)(d1 - d0);
        }
    } else {
        // 16 lanes = features, 4 nodes per wave concurrently, 2 passes
        const int f = lane & 15, sub = lane >> 4;
        for (int i = 0; i < 2; i++) {
            int node = wave * 8 + i * 4 + sub;
            long g = base + node;
            int d0 = 0, d1 = 0;
            if (g < n) { d0 = rs[g]; d1 = rs[g + 1]; }
            float acc = 0.0f;
            int e = d0;
            for (; e + 2 <= d1; e += 2) {
                int s0 = col[e], s1 = col[e + 1];
                float a0 = 0.0f, a1 = 0.0f;
                if (s0 < nvar2) {
                    a0 = srcdat[(long)((s0 < nvar) ? s0 : s0 - nvar) * 16 + f];
                    if (s0 >= nvar) a0 = -a0;
                }
                if (s1 < nvar2) {
                    a1 = srcdat[(long)((s1 < nvar) ? s1 : s1 - nvar) * 16 + f];
                    if (s1 >= nvar) a1 = -a1;
                }
                acc += a0 + a1;
            }
            for (; e < d1; e++) {
                int s = col[e];
                if (s < nvar2) {
                    float a = srcdat[(long)((s < nvar) ? s : s - nvar) * 16 + f];
                    acc += (s < nvar) ? a : -a;
                }
            }
            actA[node * AS + f] = acc;
            if (f == 0) ldeg[node] = (float)(d1 - d0);
        }
    }
    __syncthreads();

    // ---- layer0: msg = gather@W0 + deg*b0 -> actB[:, 0:64]
    gemm_layer<2>(actA, W0, b0, ldeg, wchunk, K0, K0, false, actB, nullptr, base, n);
    // stage x -> actB cols 64..66, zero col 67
    for (int idx = tid; idx < BM * 3; idx += TPB) {
        int node = idx / 3, j = idx % 3;
        float v = (base + node < n) ? xg[(base + node) * 3 + j] : 0.0f;
        actB[node * AS + 64 + j] = v;
    }
    if (tid < BM) actB[tid * AS + 67] = 0.0f;

    // ---- update MLP
    gemm_layer<4>(actB, uW1, ub1, nullptr, wchunk, 67, 68, true, actA, nullptr, base, n);
    gemm_layer<4>(actA, uW2, ub2, nullptr, wchunk, 128, 128, true, actB, nullptr, base, n);
    gemm_layer<2>(actB, uW3, ub3, nullptr, wchunk, 128, 128, false, actA, state_g, base, n);

    // ---- predictor MLP
    gemm_layer<4>(actA, pW1, pb1, nullptr, wchunk, 64, 64, true, actB, nullptr, base, n);
    gemm_layer<4>(actB, pW2, pb2, nullptr, wchunk, 128, 128, true, actA, nullptr, base, n);

    // ---- predictor layer3: 128 -> 2
    for (int i = tid; i < 64; i += TPB)
        ((float4*)wchunk)[i] = ((const float4*)pW3)[i];
    __syncthreads();
    if (tid < 128) {
        int r = tid >> 1, c = tid & 1;
        float acc = pb3[c];
        for (int k = 0; k < 128; k += 4) {
            float4 a = *(const float4*)(actA + r * AS + k);
            acc = fmaf(a.x, wchunk[(k + 0) * 2 + c], acc);
            acc = fmaf(a.y, wchunk[(k + 1) * 2 + c], acc);
            acc = fmaf(a.z, wchunk[(k + 2) * 2 + c], acc);
            acc = fmaf(a.w, wchunk[(k + 3) * 2 + c], acc);
        }
        if (base + r < n) outg[(base + r) * 2 + c] = acc;
    }
}

// ===========================================================================
extern "C" void kernel_launch(void* const* d_in, const int* in_sizes, int n_in,
                              void* d_out, int out_size, void* d_ws, size_t ws_size,
                              hipStream_t stream)
{
    const float* x    = (const float*)d_in[0];
    const int*   ei   = (const int*)d_in[1];
    // d_in[2] = gate_type: fixed ordering [VAR*nvar, NEGVAR*nvar, CLAUSE*ncla]
    const float* posr = (const float*)d_in[3];
    const float* Wr   = (const float*)d_in[4];
    const float* br   = (const float*)d_in[5];
    const float* Wc   = (const float*)d_in[6];
    const float* bc   = (const float*)d_in[7];
    const float* uW1  = (const float*)d_in[8];
    const float* ub1  = (const float*)d_in[9];
    const float* uW2  = (const float*)d_in[10];
    const float* ub2  = (const float*)d_in[11];
    const float* uW3  = (const float*)d_in[12];
    const float* ub3  = (const float*)d_in[13];
    const float* pW1  = (const float*)d_in[14];
    const float* pb1  = (const float*)d_in[15];
    const float* pW2  = (const float*)d_in[16];
    const float* pb2  = (const float*)d_in[17];
    const float* pW3  = (const float*)d_in[18];
    const float* pb3  = (const float*)d_in[19];

    const int N     = in_sizes[0] / 3;
    const int E     = in_sizes[1] / 2;
    const int nvar  = in_sizes[3] / 16;
    const int nvar2 = 2 * nvar;
    const int ncla  = N - nvar2;

    // workspace carve-out
    int* cnt    = (int*)d_ws;              // [N]
    int* rs     = cnt + N;                 // [N+1]
    int* cursor = rs + N + 1;              // [N]
    int* part   = cursor + N;              // [2048]
    int* col    = part + 2048;             // [E]
    size_t foff = ((size_t)(col + E - (int*)d_ws) + 3) & ~(size_t)3;
    float* state = (float*)d_ws + foff;    // [2nvar*64]

    hipMemsetAsync(cnt, 0, (size_t)N * sizeof(int), stream);

    const int nb = (N + 2047) / 2048;
    count_kernel<<<(E + 255) / 256, 256, 0, stream>>>(ei, cnt, E);
    scan_blocks<<<nb, 256, 0, stream>>>(cnt, rs, part, N);
    scan_part<<<1, 256, 0, stream>>>(part, nb);
    scan_fixup<<<(N + 255) / 256, 256, 0, stream>>>(rs, cursor, part, N, E);
    scatter_kernel<<<(E + 255) / 256, 256, 0, stream>>>(ei, cursor, col, E);

    {   // var + negvar partitions (gather pos_random via CSR)
        int blocks = (nvar2 + BM - 1) / BM;
        fused_kernel<16><<<blocks, TPB, 0, stream>>>(
            rs, col, posr, nvar, x, Wr, br,
            uW1, ub1, uW2, ub2, uW3, ub3,
            pW1, pb1, pW2, pb2, pW3, pb3,
            state, (float*)d_out, nvar2);
    }

    {   // clause partition (gather state via CSR, rows offset by 2nvar)
        int blocks = (ncla + BM - 1) / BM;
        fused_kernel<64><<<blocks, TPB, 0, stream>>>(
            rs + nvar2, col, state, nvar, x + (size_t)nvar2 * 3, Wc, bc,
            uW1, ub1, uW2, ub2, uW3, ub3,
            pW1, pb1, pW2, pb2, pW3, pb3,
            nullptr, (float*)d_out + (size_t)nvar2 * 2, ncla);
    }
}